// Round 1
// baseline (1199.234 us; speedup 1.0000x reference)
//
#include <hip/hip_runtime.h>
#include <hip/hip_bf16.h>
#include <math.h>

#define N_NODES 20000
#define N_EDGES 480000
#define HIDDEN  128
#define ZDIM    384        // 2*HIDDEN + EDGE_FEAT
#define NOUT    256        // 2*HIDDEN
#define BN_EPS  1e-5f

#define LDA 392            // 384 + 8 pad (bf16 elems) -> row stride 784B, 2-way-free banks
#define LDZ 264            // 256 + 8 pad for zn tile

using bf16x8 = __attribute__((ext_vector_type(8))) short;
using f32x4  = __attribute__((ext_vector_type(4))) float;
using s16x4  = __attribute__((ext_vector_type(4))) short;

__device__ __forceinline__ unsigned short f2b(float f) {
    union { float f; unsigned u; } v; v.f = f;
    unsigned r = v.u + 0x7fffu + ((v.u >> 16) & 1u);   // RTNE
    return (unsigned short)(r >> 16);
}
__device__ __forceinline__ float b2f(unsigned short s) {
    union { unsigned u; float f; } v; v.u = ((unsigned)s) << 16;
    return v.f;
}
__device__ __forceinline__ float sigmoid_(float x) {
    return 1.f / (1.f + __expf(-x));
}
__device__ __forceinline__ float softplus_(float x) {
    // jax.nn.softplus: max(x,0) + log1p(exp(-|x|))
    return fmaxf(x, 0.f) + log1pf(__expf(-fabsf(x)));
}

// ---- W [384][256] f32  ->  Wt [256][384] bf16 ----------------------------
__global__ void convW(const float* __restrict__ W, short* __restrict__ wt) {
    int n = blockIdx.x;                     // 0..255 output col
    for (int k = threadIdx.x; k < ZDIM; k += 256)
        wt[n * ZDIM + k] = (short)f2b(W[(size_t)k * NOUT + n]);
}

// ---- finalize BN stats: scaleC = gamma*invstd, shiftC = beta - mean*scaleC
__global__ void bn_finalize(const float* __restrict__ stats,
                            const float* __restrict__ gamma,
                            const float* __restrict__ beta,
                            float* __restrict__ scaleC,
                            float* __restrict__ shiftC) {
    int c = threadIdx.x;                    // 256
    float s = 0.f, q = 0.f;
    #pragma unroll
    for (int p = 0; p < 8; ++p) {
        s += stats[p * 512 + c];
        q += stats[p * 512 + 256 + c];
    }
    const float invE = 1.f / (float)N_EDGES;
    float m   = s * invE;                    // mean of pre-bias z (b cancels in BN)
    float var = q * invE - m * m;
    float inv = rsqrtf(var + BN_EPS);
    float sc  = gamma[c] * inv;
    scaleC[c] = sc;
    shiftC[c] = beta[c] - m * sc;
}

// ---- main edge GEMM; STATS pass accumulates sum/sumsq, else normalize+gate+scatter
template<bool STATS>
__global__ __launch_bounds__(256)
void edge_gemm(const float* __restrict__ h, const float* __restrict__ e,
               const int* __restrict__ src, const int* __restrict__ dst,
               const short* __restrict__ wt,
               float* __restrict__ stats,
               const float* __restrict__ scaleC, const float* __restrict__ shiftC,
               float* __restrict__ agg) {
    const int tid  = threadIdx.x;
    const int bm   = blockIdx.x;
    const int rowBase = bm * 64;
    const int lane = tid & 63;

    __shared__ __align__(16) short lds[64 * LDA];   // 50176 B; reused for zn tile

    // ---- stage A tile: 64 rows x 384 feats, gathered, f32 -> bf16 ----
    #pragma unroll
    for (int it = 0; it < 12; ++it) {
        int u   = tid + it * 256;           // 0..3071 ; 48 8-float segs per row
        int r   = u / 48;
        int seg = u - r * 48;
        int f0  = seg * 8;
        const float* p;
        if (f0 < 128)      p = h + (size_t)src[rowBase + r] * HIDDEN + f0;
        else if (f0 < 256) p = h + (size_t)dst[rowBase + r] * HIDDEN + (f0 - 128);
        else               p = e + (size_t)(rowBase + r) * HIDDEN + (f0 - 256);
        float4 x0 = *(const float4*)p;
        float4 x1 = *(const float4*)(p + 4);
        bf16x8 pk;
        pk[0] = (short)f2b(x0.x); pk[1] = (short)f2b(x0.y);
        pk[2] = (short)f2b(x0.z); pk[3] = (short)f2b(x0.w);
        pk[4] = (short)f2b(x1.x); pk[5] = (short)f2b(x1.y);
        pk[6] = (short)f2b(x1.z); pk[7] = (short)f2b(x1.w);
        *(bf16x8*)&lds[r * LDA + f0] = pk;
    }
    __syncthreads();

    // ---- K loop: wave w owns cols [w*64, w*64+64) over all 64 rows ----
    const int wcol = (tid >> 6) * 64;
    const int brow = lane & 15;
    const int kgrp = (lane >> 4) * 8;

    f32x4 acc[4][4] = {};                   // [m-frag][n-frag]
    #pragma unroll 1
    for (int kk = 0; kk < 12; ++kk) {
        int k0 = kk * 32 + kgrp;
        bf16x8 a_[4], b_[4];
        #pragma unroll
        for (int m = 0; m < 4; ++m)
            a_[m] = *(const bf16x8*)&lds[(m * 16 + brow) * LDA + k0];
        #pragma unroll
        for (int n = 0; n < 4; ++n)
            b_[n] = *(const bf16x8*)&wt[(size_t)(wcol + n * 16 + brow) * ZDIM + k0];
        #pragma unroll
        for (int m = 0; m < 4; ++m)
            #pragma unroll
            for (int n = 0; n < 4; ++n)
                acc[m][n] = __builtin_amdgcn_mfma_f32_16x16x32_bf16(
                                a_[m], b_[n], acc[m][n], 0, 0, 0);
    }

    if (STATS) {
        // per-column sum / sumsq over this block's 64 rows, 8-way-split atomics
        float* base = stats + (size_t)(bm & 7) * 512;
        #pragma unroll
        for (int n = 0; n < 4; ++n) {
            float s = 0.f, q = 0.f;
            #pragma unroll
            for (int m = 0; m < 4; ++m)
                #pragma unroll
                for (int r = 0; r < 4; ++r) {
                    float v = acc[m][n][r];
                    s += v; q += v * v;
                }
            s += __shfl_xor(s, 16, 64); s += __shfl_xor(s, 32, 64);
            q += __shfl_xor(q, 16, 64); q += __shfl_xor(q, 32, 64);
            if (lane < 16) {
                int col = wcol + n * 16 + lane;
                atomicAdd(base + col, s);
                atomicAdd(base + 256 + col, q);
            }
        }
    } else {
        // normalize -> bf16 zn tile in LDS -> gate -> atomic scatter
        float sc[4], sh[4];
        #pragma unroll
        for (int n = 0; n < 4; ++n) {
            int col = wcol + n * 16 + brow;
            sc[n] = scaleC[col];
            sh[n] = shiftC[col];
        }
        __syncthreads();                    // all waves done reading A tile
        #pragma unroll
        for (int m = 0; m < 4; ++m) {
            int rowb = m * 16 + (lane >> 4) * 4;
            #pragma unroll
            for (int n = 0; n < 4; ++n) {
                int col = wcol + n * 16 + brow;
                #pragma unroll
                for (int r = 0; r < 4; ++r) {
                    float zn = acc[m][n][r] * sc[n] + sh[n];
                    lds[(rowb + r) * LDZ + col] = (short)f2b(zn);
                }
            }
        }
        __syncthreads();

        const int c0 = (tid & 31) * 4;      // 4 msg cols per thread
        const int r0 = tid >> 5;            // 8 row groups
        #pragma unroll
        for (int rp = 0; rp < 8; ++rp) {
            int row = rp * 8 + r0;
            int d   = dst[rowBase + row];
            float* ap = agg + (size_t)d * HIDDEN + c0;
            s16x4 f4 = *(const s16x4*)&lds[row * LDZ + c0];
            s16x4 c4 = *(const s16x4*)&lds[row * LDZ + 128 + c0];
            #pragma unroll
            for (int j = 0; j < 4; ++j) {
                float fv  = b2f((unsigned short)f4[j]);
                float cv  = b2f((unsigned short)c4[j]);
                float msg = sigmoid_(fv) * softplus_(cv);
                atomicAdd(ap + j, msg);
            }
        }
    }
}

// ---- out = softplus(h + agg), in place over d_out -------------------------
__global__ void node_finalize(const float* __restrict__ h, float* __restrict__ out) {
    int i = blockIdx.x * 256 + threadIdx.x;      // over float4s: 640000 total
    float4 hv = ((const float4*)h)[i];
    float4 av = ((float4*)out)[i];
    float4 r;
    r.x = softplus_(hv.x + av.x);
    r.y = softplus_(hv.y + av.y);
    r.z = softplus_(hv.z + av.z);
    r.w = softplus_(hv.w + av.w);
    ((float4*)out)[i] = r;
}

extern "C" void kernel_launch(void* const* d_in, const int* in_sizes, int n_in,
                              void* d_out, int out_size, void* d_ws, size_t ws_size,
                              hipStream_t stream) {
    const float* h     = (const float*)d_in[0];
    const float* e     = (const float*)d_in[1];
    const int*   src   = (const int*)d_in[2];
    const int*   dst   = (const int*)d_in[3];
    const float* W     = (const float*)d_in[4];
    // d_in[5] = b : cancels exactly through BatchNorm -> unused
    const float* gamma = (const float*)d_in[6];
    const float* beta  = (const float*)d_in[7];
    float* out = (float*)d_out;

    char*  ws     = (char*)d_ws;
    float* stats  = (float*)ws;                 // 8 * 512 floats = 16 KB
    float* scaleC = (float*)(ws + 16384);       // 256 floats
    float* shiftC = (float*)(ws + 17408);       // 256 floats
    short* wt     = (short*)(ws + 18432);       // 256*384 bf16 = 192 KB

    hipMemsetAsync(stats, 0, 16384, stream);
    hipMemsetAsync(out, 0, (size_t)N_NODES * HIDDEN * sizeof(float), stream);

    convW<<<NOUT, 256, 0, stream>>>(W, wt);
    edge_gemm<true ><<<N_EDGES / 64, 256, 0, stream>>>(h, e, src, dst, wt,
                                                       stats, nullptr, nullptr, nullptr);
    bn_finalize<<<1, 256, 0, stream>>>(stats, gamma, beta, scaleC, shiftC);
    edge_gemm<false><<<N_EDGES / 64, 256, 0, stream>>>(h, e, src, dst, wt,
                                                       stats, scaleC, shiftC, out);
    node_finalize<<<N_NODES * HIDDEN / (4 * 256), 256, 0, stream>>>(h, out);
}

// Round 2
// 617.982 us; speedup vs baseline: 1.9406x; 1.9406x over previous
//
#include <hip/hip_runtime.h>
#include <hip/hip_bf16.h>
#include <math.h>

#define N_NODES 20000
#define N_EDGES 480000
#define HIDDEN  128
#define ZDIM    384        // 2*HIDDEN + EDGE_FEAT
#define NOUT    256        // 2*HIDDEN
#define BN_EPS  1e-5f

#define LDA 392            // 384 + 8 pad (bf16 elems)
#define LDZ 264            // 256 + 8 pad for z tile

using bf16x8 = __attribute__((ext_vector_type(8))) short;
using f32x4  = __attribute__((ext_vector_type(4))) float;
using s16x4  = __attribute__((ext_vector_type(4))) short;

__device__ __forceinline__ unsigned short f2b(float f) {
    union { float f; unsigned u; } v; v.f = f;
    unsigned r = v.u + 0x7fffu + ((v.u >> 16) & 1u);   // RTNE
    return (unsigned short)(r >> 16);
}
__device__ __forceinline__ float bflo(unsigned u) {
    union { unsigned x; float f; } v; v.x = u << 16; return v.f;
}
__device__ __forceinline__ float bfhi(unsigned u) {
    union { unsigned x; float f; } v; v.x = u & 0xffff0000u; return v.f;
}
__device__ __forceinline__ float b2f(unsigned short s) {
    union { unsigned u; float f; } v; v.u = ((unsigned)s) << 16; return v.f;
}
__device__ __forceinline__ float sigmoid_(float x) {
    return 1.f / (1.f + __expf(-x));
}
__device__ __forceinline__ float softplus_(float x) {
    // max(x,0) + log1p(exp(-|x|)); __logf(1+t) is bf16-accurate and fast
    return fmaxf(x, 0.f) + __logf(1.f + __expf(-fabsf(x)));
}

// ---- W [384][256] f32  ->  Wt [256][384] bf16 ----------------------------
__global__ void convW(const float* __restrict__ W, short* __restrict__ wt) {
    int n = blockIdx.x;
    for (int k = threadIdx.x; k < ZDIM; k += 256)
        wt[n * ZDIM + k] = (short)f2b(W[(size_t)k * NOUT + n]);
}

// ---- BN stats -> scale/shift ---------------------------------------------
__global__ void bn_finalize(const float* __restrict__ stats,
                            const float* __restrict__ gamma,
                            const float* __restrict__ beta,
                            float* __restrict__ scaleC,
                            float* __restrict__ shiftC) {
    int c = threadIdx.x;
    float s = 0.f, q = 0.f;
    #pragma unroll
    for (int p = 0; p < 8; ++p) {
        s += stats[p * 512 + c];
        q += stats[p * 512 + 256 + c];
    }
    const float invE = 1.f / (float)N_EDGES;
    float m   = s * invE;                    // linear bias b cancels in BN
    float var = q * invE - m * m;
    float inv = rsqrtf(var + BN_EPS);
    float sc  = gamma[c] * inv;
    scaleC[c] = sc;
    shiftC[c] = beta[c] - m * sc;
}

// ---- counting sort of edges by dst ---------------------------------------
__global__ void hist_dst(const int* __restrict__ dst, int* __restrict__ counts) {
    int i = blockIdx.x * 256 + threadIdx.x;
    if (i < N_EDGES) atomicAdd(&counts[dst[i]], 1);
}

__global__ void scan_nodes(const int* __restrict__ counts, int* __restrict__ offs,
                           int* __restrict__ cursor) {
    __shared__ int part[1024];
    int t = threadIdx.x;
    int base = t * 20;                       // 1024*20 >= 20000
    int local[20]; int s = 0;
    #pragma unroll
    for (int k = 0; k < 20; ++k) {
        int idx = base + k;
        int v = (idx < N_NODES) ? counts[idx] : 0;
        local[k] = s; s += v;
    }
    part[t] = s; __syncthreads();
    for (int d = 1; d < 1024; d <<= 1) {
        int v = (t >= d) ? part[t - d] : 0;
        __syncthreads();
        part[t] += v;
        __syncthreads();
    }
    int pre = (t > 0) ? part[t - 1] : 0;
    #pragma unroll
    for (int k = 0; k < 20; ++k) {
        int idx = base + k;
        if (idx < N_NODES) { int o = pre + local[k]; offs[idx] = o; cursor[idx] = o; }
    }
}

__global__ void build_perm(const int* __restrict__ dst, int* __restrict__ cursor,
                           int* __restrict__ perm) {
    int i = blockIdx.x * 256 + threadIdx.x;
    if (i < N_EDGES) { int p = atomicAdd(&cursor[dst[i]], 1); perm[p] = i; }
}

// ---- edge GEMM ------------------------------------------------------------
// MODE 0: stats + raw-z bf16 write (main path, single GEMM)
// MODE 1: stats only (fallback)   MODE 2: normalize+gate+atomic scatter (fallback)
template<int MODE>
__global__ __launch_bounds__(256)
void edge_gemm(const float* __restrict__ h, const float* __restrict__ e,
               const int* __restrict__ src, const int* __restrict__ dst,
               const short* __restrict__ wt,
               float* __restrict__ stats,
               const float* __restrict__ scaleC, const float* __restrict__ shiftC,
               float* __restrict__ agg, short* __restrict__ zout) {
    const int tid  = threadIdx.x;
    const int bm   = blockIdx.x;
    const int rowBase = bm * 64;
    const int lane = tid & 63;

    __shared__ __align__(16) short lds[64 * LDA];   // reused for z tile

    // ---- stage A tile: 64 rows x 384 feats, gathered, f32 -> bf16 ----
    #pragma unroll
    for (int it = 0; it < 12; ++it) {
        int u   = tid + it * 256;
        int r   = u / 48;
        int seg = u - r * 48;
        int f0  = seg * 8;
        const float* p;
        if (f0 < 128)      p = h + (size_t)src[rowBase + r] * HIDDEN + f0;
        else if (f0 < 256) p = h + (size_t)dst[rowBase + r] * HIDDEN + (f0 - 128);
        else               p = e + (size_t)(rowBase + r) * HIDDEN + (f0 - 256);
        float4 x0 = *(const float4*)p;
        float4 x1 = *(const float4*)(p + 4);
        bf16x8 pk;
        pk[0] = (short)f2b(x0.x); pk[1] = (short)f2b(x0.y);
        pk[2] = (short)f2b(x0.z); pk[3] = (short)f2b(x0.w);
        pk[4] = (short)f2b(x1.x); pk[5] = (short)f2b(x1.y);
        pk[6] = (short)f2b(x1.z); pk[7] = (short)f2b(x1.w);
        *(bf16x8*)&lds[r * LDA + f0] = pk;
    }
    __syncthreads();

    const int wcol = (tid >> 6) * 64;
    const int brow = lane & 15;
    const int kgrp = (lane >> 4) * 8;

    f32x4 acc[4][4] = {};
    #pragma unroll 1
    for (int kk = 0; kk < 12; ++kk) {
        int k0 = kk * 32 + kgrp;
        bf16x8 a_[4], b_[4];
        #pragma unroll
        for (int m = 0; m < 4; ++m)
            a_[m] = *(const bf16x8*)&lds[(m * 16 + brow) * LDA + k0];
        #pragma unroll
        for (int n = 0; n < 4; ++n)
            b_[n] = *(const bf16x8*)&wt[(size_t)(wcol + n * 16 + brow) * ZDIM + k0];
        #pragma unroll
        for (int m = 0; m < 4; ++m)
            #pragma unroll
            for (int n = 0; n < 4; ++n)
                acc[m][n] = __builtin_amdgcn_mfma_f32_16x16x32_bf16(
                                a_[m], b_[n], acc[m][n], 0, 0, 0);
    }

    if (MODE == 0 || MODE == 1) {
        // per-column sum / sumsq, 8-way-split atomics (exact f32 stats)
        float* base = stats + (size_t)(bm & 7) * 512;
        #pragma unroll
        for (int n = 0; n < 4; ++n) {
            float s = 0.f, q = 0.f;
            #pragma unroll
            for (int m = 0; m < 4; ++m)
                #pragma unroll
                for (int r = 0; r < 4; ++r) {
                    float v = acc[m][n][r];
                    s += v; q += v * v;
                }
            s += __shfl_xor(s, 16, 64); s += __shfl_xor(s, 32, 64);
            q += __shfl_xor(q, 16, 64); q += __shfl_xor(q, 32, 64);
            if (lane < 16) {
                int col = wcol + n * 16 + lane;
                atomicAdd(base + col, s);
                atomicAdd(base + 256 + col, q);
            }
        }
    }

    if (MODE == 0) {
        // raw z -> bf16 tile in LDS -> coalesced global write
        __syncthreads();
        #pragma unroll
        for (int m = 0; m < 4; ++m) {
            int rowb = m * 16 + (lane >> 4) * 4;
            #pragma unroll
            for (int n = 0; n < 4; ++n) {
                int col = wcol + n * 16 + brow;
                #pragma unroll
                for (int r = 0; r < 4; ++r)
                    lds[(rowb + r) * LDZ + col] = (short)f2b(acc[m][n][r]);
            }
        }
        __syncthreads();
        #pragma unroll
        for (int it = 0; it < 8; ++it) {
            int chunk = tid + it * 256;      // 2048 chunks of 16B
            int r = chunk >> 5;
            int c = (chunk & 31) * 8;
            *(bf16x8*)&zout[((size_t)rowBase + r) * NOUT + c] =
                *(const bf16x8*)&lds[r * LDZ + c];
        }
    }

    if (MODE == 2) {
        float sc[4], sh[4];
        #pragma unroll
        for (int n = 0; n < 4; ++n) {
            int col = wcol + n * 16 + brow;
            sc[n] = scaleC[col];
            sh[n] = shiftC[col];
        }
        __syncthreads();
        #pragma unroll
        for (int m = 0; m < 4; ++m) {
            int rowb = m * 16 + (lane >> 4) * 4;
            #pragma unroll
            for (int n = 0; n < 4; ++n) {
                int col = wcol + n * 16 + brow;
                #pragma unroll
                for (int r = 0; r < 4; ++r) {
                    float zn = acc[m][n][r] * sc[n] + sh[n];
                    lds[(rowb + r) * LDZ + col] = (short)f2b(zn);
                }
            }
        }
        __syncthreads();
        const int c0 = (tid & 31) * 4;
        const int r0 = tid >> 5;
        #pragma unroll
        for (int rp = 0; rp < 8; ++rp) {
            int row = rp * 8 + r0;
            int d   = dst[rowBase + row];
            float* ap = agg + (size_t)d * HIDDEN + c0;
            s16x4 f4 = *(const s16x4*)&lds[row * LDZ + c0];
            s16x4 c4 = *(const s16x4*)&lds[row * LDZ + 128 + c0];
            #pragma unroll
            for (int j = 0; j < 4; ++j) {
                float fv  = b2f((unsigned short)f4[j]);
                float cv  = b2f((unsigned short)c4[j]);
                atomicAdd(ap + j, sigmoid_(fv) * softplus_(cv));
            }
        }
    }
}

// ---- per-node gather-reduce: normalize + gate + segment-sum + residual ----
__global__ __launch_bounds__(256)
void node_gather(const short* __restrict__ z, const int* __restrict__ perm,
                 const int* __restrict__ offs, const int* __restrict__ counts,
                 const float* __restrict__ scaleC, const float* __restrict__ shiftC,
                 const float* __restrict__ h, float* __restrict__ out) {
    int node = blockIdx.x * 4 + (threadIdx.x >> 6);
    int lane = threadIdx.x & 63;
    int l32  = lane & 31;
    int c0   = l32 * 4;

    float scF[4], shF[4], scS[4], shS[4];
    #pragma unroll
    for (int k = 0; k < 4; ++k) {
        scF[k] = scaleC[c0 + k];       shF[k] = shiftC[c0 + k];
        scS[k] = scaleC[128 + c0 + k]; shS[k] = shiftC[128 + c0 + k];
    }

    int s   = offs[node];
    int deg = counts[node];
    float a0 = 0.f, a1 = 0.f, a2 = 0.f, a3 = 0.f;

    // lanes 0-31 take even list slots, lanes 32-63 take odd slots
    for (int j = (lane >> 5); j < deg; j += 2) {
        int eid = perm[s + j];
        const short* zp = z + (size_t)eid * NOUT;
        uint2 f = *(const uint2*)(zp + c0);          // filter cols c0..c0+3
        uint2 c = *(const uint2*)(zp + 128 + c0);    // core   cols
        float f0 = bflo(f.x) * scF[0] + shF[0];
        float f1 = bfhi(f.x) * scF[1] + shF[1];
        float f2 = bflo(f.y) * scF[2] + shF[2];
        float f3 = bfhi(f.y) * scF[3] + shF[3];
        float g0 = bflo(c.x) * scS[0] + shS[0];
        float g1 = bfhi(c.x) * scS[1] + shS[1];
        float g2 = bflo(c.y) * scS[2] + shS[2];
        float g3 = bfhi(c.y) * scS[3] + shS[3];
        a0 += sigmoid_(f0) * softplus_(g0);
        a1 += sigmoid_(f1) * softplus_(g1);
        a2 += sigmoid_(f2) * softplus_(g2);
        a3 += sigmoid_(f3) * softplus_(g3);
    }
    a0 += __shfl_xor(a0, 32, 64);
    a1 += __shfl_xor(a1, 32, 64);
    a2 += __shfl_xor(a2, 32, 64);
    a3 += __shfl_xor(a3, 32, 64);

    if (lane < 32) {
        size_t o = (size_t)node * HIDDEN + c0;
        float4 hv = *(const float4*)&h[o];
        float4 r;
        r.x = softplus_(hv.x + a0);
        r.y = softplus_(hv.y + a1);
        r.z = softplus_(hv.z + a2);
        r.w = softplus_(hv.w + a3);
        *(float4*)&out[o] = r;
    }
}

// ---- fallback finalize ----------------------------------------------------
__global__ void node_finalize(const float* __restrict__ h, float* __restrict__ out) {
    int i = blockIdx.x * 256 + threadIdx.x;
    float4 hv = ((const float4*)h)[i];
    float4 av = ((float4*)out)[i];
    float4 r;
    r.x = softplus_(hv.x + av.x);
    r.y = softplus_(hv.y + av.y);
    r.z = softplus_(hv.z + av.z);
    r.w = softplus_(hv.w + av.w);
    ((float4*)out)[i] = r;
}

extern "C" void kernel_launch(void* const* d_in, const int* in_sizes, int n_in,
                              void* d_out, int out_size, void* d_ws, size_t ws_size,
                              hipStream_t stream) {
    const float* h     = (const float*)d_in[0];
    const float* e     = (const float*)d_in[1];
    const int*   srcp  = (const int*)d_in[2];
    const int*   dstp  = (const int*)d_in[3];
    const float* W     = (const float*)d_in[4];
    // d_in[5] = b : cancels through BatchNorm
    const float* gamma = (const float*)d_in[6];
    const float* beta  = (const float*)d_in[7];
    float* out = (float*)d_out;

    char*  ws     = (char*)d_ws;
    float* stats  = (float*)ws;                 // 16 KB
    float* scaleC = (float*)(ws + 16384);
    float* shiftC = (float*)(ws + 17408);
    short* wt     = (short*)(ws + 18432);       // 192 KB -> 215040
    int*   counts = (int*)(ws + 215040);        // 80128-byte slots
    int*   offs   = (int*)(ws + 295168);
    int*   cursor = (int*)(ws + 375296);
    int*   perm   = (int*)(ws + 455424);        // 1.92 MB -> 2375424
    short* zbuf   = (short*)(ws + 2375424);     // 245.76 MB
    const size_t need = 2375424ull + (size_t)N_EDGES * NOUT * 2;

    hipMemsetAsync(stats, 0, 16384, stream);
    convW<<<NOUT, 256, 0, stream>>>(W, wt);

    if (ws_size >= need) {
        hipMemsetAsync(counts, 0, N_NODES * sizeof(int), stream);
        hist_dst<<<(N_EDGES + 255) / 256, 256, 0, stream>>>(dstp, counts);
        scan_nodes<<<1, 1024, 0, stream>>>(counts, offs, cursor);
        build_perm<<<(N_EDGES + 255) / 256, 256, 0, stream>>>(dstp, cursor, perm);

        edge_gemm<0><<<N_EDGES / 64, 256, 0, stream>>>(h, e, srcp, dstp, wt,
                stats, nullptr, nullptr, nullptr, zbuf);
        bn_finalize<<<1, 256, 0, stream>>>(stats, gamma, beta, scaleC, shiftC);
        node_gather<<<N_NODES / 4, 256, 0, stream>>>(zbuf, perm, offs, counts,
                scaleC, shiftC, h, out);
    } else {
        hipMemsetAsync(out, 0, (size_t)N_NODES * HIDDEN * sizeof(float), stream);
        edge_gemm<1><<<N_EDGES / 64, 256, 0, stream>>>(h, e, srcp, dstp, wt,
                stats, nullptr, nullptr, nullptr, nullptr);
        bn_finalize<<<1, 256, 0, stream>>>(stats, gamma, beta, scaleC, shiftC);
        edge_gemm<2><<<N_EDGES / 64, 256, 0, stream>>>(h, e, srcp, dstp, wt,
                stats, scaleC, shiftC, out, nullptr);
        node_finalize<<<N_NODES * HIDDEN / (4 * 256), 256, 0, stream>>>(h, out);
    }
}

// Round 3
// 596.202 us; speedup vs baseline: 2.0115x; 1.0365x over previous
//
#include <hip/hip_runtime.h>
#include <hip/hip_bf16.h>
#include <math.h>

#define N_NODES 20000
#define N_EDGES 480000
#define HIDDEN  128
#define ZDIM    384        // 2*HIDDEN + EDGE_FEAT
#define NOUT    256        // 2*HIDDEN
#define BN_EPS  1e-5f

#define LDA 392            // 384 + 8 pad (bf16 elems)
#define LDZ 264            // 256 + 8 pad for z tile

using bf16x8 = __attribute__((ext_vector_type(8))) short;
using f32x4  = __attribute__((ext_vector_type(4))) float;
using s16x4  = __attribute__((ext_vector_type(4))) short;

__device__ __forceinline__ unsigned short f2b(float f) {
    union { float f; unsigned u; } v; v.f = f;
    unsigned r = v.u + 0x7fffu + ((v.u >> 16) & 1u);   // RTNE
    return (unsigned short)(r >> 16);
}
__device__ __forceinline__ float bflo(unsigned u) {
    union { unsigned x; float f; } v; v.x = u << 16; return v.f;
}
__device__ __forceinline__ float bfhi(unsigned u) {
    union { unsigned x; float f; } v; v.x = u & 0xffff0000u; return v.f;
}
__device__ __forceinline__ float b2f(unsigned short s) {
    union { unsigned u; float f; } v; v.u = ((unsigned)s) << 16; return v.f;
}
__device__ __forceinline__ float sigmoid_(float x) {
    return 1.f / (1.f + __expf(-x));
}
__device__ __forceinline__ float softplus_(float x) {
    return fmaxf(x, 0.f) + __logf(1.f + __expf(-fabsf(x)));
}

// ---- W [384][256] f32  ->  Wt [256][384] bf16 ----------------------------
__global__ void convW(const float* __restrict__ W, short* __restrict__ wt) {
    int n = blockIdx.x;
    for (int k = threadIdx.x; k < ZDIM; k += 256)
        wt[n * ZDIM + k] = (short)f2b(W[(size_t)k * NOUT + n]);
}

// ---- BN stats -> scale/shift ---------------------------------------------
__global__ void bn_finalize(const float* __restrict__ stats,
                            const float* __restrict__ gamma,
                            const float* __restrict__ beta,
                            float* __restrict__ scaleC,
                            float* __restrict__ shiftC) {
    int c = threadIdx.x;
    float s = 0.f, q = 0.f;
    #pragma unroll
    for (int p = 0; p < 8; ++p) {
        s += stats[p * 512 + c];
        q += stats[p * 512 + 256 + c];
    }
    const float invE = 1.f / (float)N_EDGES;
    float m   = s * invE;                    // linear bias b cancels in BN
    float var = q * invE - m * m;
    float inv = rsqrtf(var + BN_EPS);
    float sc  = gamma[c] * inv;
    scaleC[c] = sc;
    shiftC[c] = beta[c] - m * sc;
}

// ---- counting sort of edges by dst ---------------------------------------
__global__ void hist_dst(const int* __restrict__ dst, int* __restrict__ counts) {
    int i = blockIdx.x * 256 + threadIdx.x;
    if (i < N_EDGES) atomicAdd(&counts[dst[i]], 1);
}

__global__ void scan_nodes(const int* __restrict__ counts, int* __restrict__ offs,
                           int* __restrict__ cursor) {
    __shared__ int part[1024];
    int t = threadIdx.x;
    int base = t * 20;
    int local[20]; int s = 0;
    #pragma unroll
    for (int k = 0; k < 20; ++k) {
        int idx = base + k;
        int v = (idx < N_NODES) ? counts[idx] : 0;
        local[k] = s; s += v;
    }
    part[t] = s; __syncthreads();
    for (int d = 1; d < 1024; d <<= 1) {
        int v = (t >= d) ? part[t - d] : 0;
        __syncthreads();
        part[t] += v;
        __syncthreads();
    }
    int pre = (t > 0) ? part[t - 1] : 0;
    #pragma unroll
    for (int k = 0; k < 20; ++k) {
        int idx = base + k;
        if (idx < N_NODES) { int o = pre + local[k]; offs[idx] = o; cursor[idx] = o; }
    }
}

__global__ void build_perm(const int* __restrict__ dst, int* __restrict__ cursor,
                           int* __restrict__ perm) {
    int i = blockIdx.x * 256 + threadIdx.x;
    if (i < N_EDGES) { int p = atomicAdd(&cursor[dst[i]], 1); perm[p] = i; }
}

// ---- edge GEMM ------------------------------------------------------------
// MODE 0: stats + raw-z bf16 write (main path, single GEMM)
// MODE 1: stats only (fallback)   MODE 2: normalize+gate+atomic scatter (fallback)
template<int MODE>
__global__ __launch_bounds__(256)
void edge_gemm(const float* __restrict__ h, const float* __restrict__ e,
               const int* __restrict__ src, const int* __restrict__ dst,
               const short* __restrict__ wt,
               float* __restrict__ stats,
               const float* __restrict__ scaleC, const float* __restrict__ shiftC,
               float* __restrict__ agg, short* __restrict__ zout) {
    const int tid  = threadIdx.x;
    const int bm   = blockIdx.x;
    const int rowBase = bm * 64;
    const int lane = tid & 63;

    __shared__ __align__(16) short lds[64 * LDA];   // reused for z tile

    // ---- stage A tile: 64 rows x 384 feats, gathered, f32 -> bf16 ----
    #pragma unroll
    for (int it = 0; it < 12; ++it) {
        int u   = tid + it * 256;
        int r   = u / 48;
        int seg = u - r * 48;
        int f0  = seg * 8;
        const float* p;
        if (f0 < 128)      p = h + (size_t)src[rowBase + r] * HIDDEN + f0;
        else if (f0 < 256) p = h + (size_t)dst[rowBase + r] * HIDDEN + (f0 - 128);
        else               p = e + (size_t)(rowBase + r) * HIDDEN + (f0 - 256);
        float4 x0 = *(const float4*)p;
        float4 x1 = *(const float4*)(p + 4);
        bf16x8 pk;
        pk[0] = (short)f2b(x0.x); pk[1] = (short)f2b(x0.y);
        pk[2] = (short)f2b(x0.z); pk[3] = (short)f2b(x0.w);
        pk[4] = (short)f2b(x1.x); pk[5] = (short)f2b(x1.y);
        pk[6] = (short)f2b(x1.z); pk[7] = (short)f2b(x1.w);
        *(bf16x8*)&lds[r * LDA + f0] = pk;
    }
    __syncthreads();

    const int wcol = (tid >> 6) * 64;
    const int brow = lane & 15;
    const int kgrp = (lane >> 4) * 8;

    // ---- K loop, manually software-pipelined one deep ----
    const short* wB[4];
    #pragma unroll
    for (int n = 0; n < 4; ++n)
        wB[n] = wt + (size_t)(wcol + n * 16 + brow) * ZDIM + kgrp;
    const short* aP = &lds[brow * LDA + kgrp];

    f32x4 acc[4][4] = {};
    bf16x8 aC[4], bC[4];
    #pragma unroll
    for (int m = 0; m < 4; ++m) aC[m] = *(const bf16x8*)(aP + m * 16 * LDA);
    #pragma unroll
    for (int n = 0; n < 4; ++n) bC[n] = *(const bf16x8*)(wB[n]);

    #pragma unroll
    for (int kk = 0; kk < 12; ++kk) {
        bf16x8 aN[4], bN[4];
        if (kk < 11) {
            const int k0 = (kk + 1) * 32;
            #pragma unroll
            for (int n = 0; n < 4; ++n) bN[n] = *(const bf16x8*)(wB[n] + k0);
            #pragma unroll
            for (int m = 0; m < 4; ++m) aN[m] = *(const bf16x8*)(aP + m * 16 * LDA + k0);
        }
        #pragma unroll
        for (int m = 0; m < 4; ++m)
            #pragma unroll
            for (int n = 0; n < 4; ++n)
                acc[m][n] = __builtin_amdgcn_mfma_f32_16x16x32_bf16(
                                aC[m], bC[n], acc[m][n], 0, 0, 0);
        if (kk < 11) {
            #pragma unroll
            for (int m = 0; m < 4; ++m) aC[m] = aN[m];
            #pragma unroll
            for (int n = 0; n < 4; ++n) bC[n] = bN[n];
        }
    }

    if (MODE == 0 || MODE == 1) {
        float* base = stats + (size_t)(bm & 7) * 512;
        #pragma unroll
        for (int n = 0; n < 4; ++n) {
            float s = 0.f, q = 0.f;
            #pragma unroll
            for (int m = 0; m < 4; ++m)
                #pragma unroll
                for (int r = 0; r < 4; ++r) {
                    float v = acc[m][n][r];
                    s += v; q += v * v;
                }
            s += __shfl_xor(s, 16, 64); s += __shfl_xor(s, 32, 64);
            q += __shfl_xor(q, 16, 64); q += __shfl_xor(q, 32, 64);
            if (lane < 16) {
                int col = wcol + n * 16 + lane;
                atomicAdd(base + col, s);
                atomicAdd(base + 256 + col, q);
            }
        }
    }

    if (MODE == 0) {
        __syncthreads();
        #pragma unroll
        for (int m = 0; m < 4; ++m) {
            int rowb = m * 16 + (lane >> 4) * 4;
            #pragma unroll
            for (int n = 0; n < 4; ++n) {
                int col = wcol + n * 16 + brow;
                #pragma unroll
                for (int r = 0; r < 4; ++r)
                    lds[(rowb + r) * LDZ + col] = (short)f2b(acc[m][n][r]);
            }
        }
        __syncthreads();
        #pragma unroll
        for (int it = 0; it < 8; ++it) {
            int chunk = tid + it * 256;
            int r = chunk >> 5;
            int c = (chunk & 31) * 8;
            *(bf16x8*)&zout[((size_t)rowBase + r) * NOUT + c] =
                *(const bf16x8*)&lds[r * LDZ + c];
        }
    }

    if (MODE == 2) {
        float sc[4], sh[4];
        #pragma unroll
        for (int n = 0; n < 4; ++n) {
            int col = wcol + n * 16 + brow;
            sc[n] = scaleC[col];
            sh[n] = shiftC[col];
        }
        __syncthreads();
        #pragma unroll
        for (int m = 0; m < 4; ++m) {
            int rowb = m * 16 + (lane >> 4) * 4;
            #pragma unroll
            for (int n = 0; n < 4; ++n) {
                int col = wcol + n * 16 + brow;
                #pragma unroll
                for (int r = 0; r < 4; ++r) {
                    float zn = acc[m][n][r] * sc[n] + sh[n];
                    lds[(rowb + r) * LDZ + col] = (short)f2b(zn);
                }
            }
        }
        __syncthreads();
        const int c0 = (tid & 31) * 4;
        const int r0 = tid >> 5;
        #pragma unroll
        for (int rp = 0; rp < 8; ++rp) {
            int row = rp * 8 + r0;
            int d   = dst[rowBase + row];
            float* ap = agg + (size_t)d * HIDDEN + c0;
            s16x4 f4 = *(const s16x4*)&lds[row * LDZ + c0];
            s16x4 c4 = *(const s16x4*)&lds[row * LDZ + 128 + c0];
            #pragma unroll
            for (int j = 0; j < 4; ++j) {
                float fv  = b2f((unsigned short)f4[j]);
                float cv  = b2f((unsigned short)c4[j]);
                atomicAdd(ap + j, sigmoid_(fv) * softplus_(cv));
            }
        }
    }
}

// ---- per-node gather-reduce: normalize + gate + segment-sum + residual ----
__global__ __launch_bounds__(256)
void node_gather(const short* __restrict__ z, const int* __restrict__ perm,
                 const int* __restrict__ offs, const int* __restrict__ counts,
                 const float* __restrict__ scaleC, const float* __restrict__ shiftC,
                 const float* __restrict__ h, float* __restrict__ out) {
    int node = blockIdx.x * 4 + (threadIdx.x >> 6);
    int lane = threadIdx.x & 63;
    int l32  = lane & 31;
    int c0   = l32 * 4;

    float scF[4], shF[4], scS[4], shS[4];
    #pragma unroll
    for (int k = 0; k < 4; ++k) {
        scF[k] = scaleC[c0 + k];       shF[k] = shiftC[c0 + k];
        scS[k] = scaleC[128 + c0 + k]; shS[k] = shiftC[128 + c0 + k];
    }

    int s   = offs[node];
    int deg = counts[node];
    float a0 = 0.f, a1 = 0.f, a2 = 0.f, a3 = 0.f;

    // lanes 0-31: slots 0,2,4,..; lanes 32-63: slots 1,3,5,..; 2 edges in flight
    for (int j = (lane >> 5); j < deg; j += 4) {
        int jB = j + 2;
        bool hasB = (jB < deg);
        int eA = perm[s + j];
        int eB = hasB ? perm[s + jB] : eA;
        const short* zA = z + (size_t)eA * NOUT + c0;
        const short* zB = z + (size_t)eB * NOUT + c0;
        uint2 fA = *(const uint2*)zA;
        uint2 cA = *(const uint2*)(zA + 128);
        uint2 fB = *(const uint2*)zB;
        uint2 cB = *(const uint2*)(zB + 128);

        float f0 = bflo(fA.x) * scF[0] + shF[0];
        float f1 = bfhi(fA.x) * scF[1] + shF[1];
        float f2 = bflo(fA.y) * scF[2] + shF[2];
        float f3 = bfhi(fA.y) * scF[3] + shF[3];
        float g0 = bflo(cA.x) * scS[0] + shS[0];
        float g1 = bfhi(cA.x) * scS[1] + shS[1];
        float g2 = bflo(cA.y) * scS[2] + shS[2];
        float g3 = bfhi(cA.y) * scS[3] + shS[3];
        a0 += sigmoid_(f0) * softplus_(g0);
        a1 += sigmoid_(f1) * softplus_(g1);
        a2 += sigmoid_(f2) * softplus_(g2);
        a3 += sigmoid_(f3) * softplus_(g3);

        if (hasB) {
            f0 = bflo(fB.x) * scF[0] + shF[0];
            f1 = bfhi(fB.x) * scF[1] + shF[1];
            f2 = bflo(fB.y) * scF[2] + shF[2];
            f3 = bfhi(fB.y) * scF[3] + shF[3];
            g0 = bflo(cB.x) * scS[0] + shS[0];
            g1 = bfhi(cB.x) * scS[1] + shS[1];
            g2 = bflo(cB.y) * scS[2] + shS[2];
            g3 = bfhi(cB.y) * scS[3] + shS[3];
            a0 += sigmoid_(f0) * softplus_(g0);
            a1 += sigmoid_(f1) * softplus_(g1);
            a2 += sigmoid_(f2) * softplus_(g2);
            a3 += sigmoid_(f3) * softplus_(g3);
        }
    }
    a0 += __shfl_xor(a0, 32, 64);
    a1 += __shfl_xor(a1, 32, 64);
    a2 += __shfl_xor(a2, 32, 64);
    a3 += __shfl_xor(a3, 32, 64);

    if (lane < 32) {
        size_t o = (size_t)node * HIDDEN + c0;
        float4 hv = *(const float4*)&h[o];
        float4 r;
        r.x = softplus_(hv.x + a0);
        r.y = softplus_(hv.y + a1);
        r.z = softplus_(hv.z + a2);
        r.w = softplus_(hv.w + a3);
        *(float4*)&out[o] = r;
    }
}

// ---- fallback finalize ----------------------------------------------------
__global__ void node_finalize(const float* __restrict__ h, float* __restrict__ out) {
    int i = blockIdx.x * 256 + threadIdx.x;
    float4 hv = ((const float4*)h)[i];
    float4 av = ((float4*)out)[i];
    float4 r;
    r.x = softplus_(hv.x + av.x);
    r.y = softplus_(hv.y + av.y);
    r.z = softplus_(hv.z + av.z);
    r.w = softplus_(hv.w + av.w);
    ((float4*)out)[i] = r;
}

extern "C" void kernel_launch(void* const* d_in, const int* in_sizes, int n_in,
                              void* d_out, int out_size, void* d_ws, size_t ws_size,
                              hipStream_t stream) {
    const float* h     = (const float*)d_in[0];
    const float* e     = (const float*)d_in[1];
    const int*   srcp  = (const int*)d_in[2];
    const int*   dstp  = (const int*)d_in[3];
    const float* W     = (const float*)d_in[4];
    // d_in[5] = b : cancels through BatchNorm
    const float* gamma = (const float*)d_in[6];
    const float* beta  = (const float*)d_in[7];
    float* out = (float*)d_out;

    char*  ws     = (char*)d_ws;
    float* stats  = (float*)ws;                 // 16 KB
    float* scaleC = (float*)(ws + 16384);
    float* shiftC = (float*)(ws + 17408);
    short* wt     = (short*)(ws + 18432);       // 192 KB -> 215040
    int*   counts = (int*)(ws + 215040);
    int*   offs   = (int*)(ws + 295168);
    int*   cursor = (int*)(ws + 375296);
    int*   perm   = (int*)(ws + 455424);        // -> 2375424
    short* zbuf   = (short*)(ws + 2375424);     // 245.76 MB
    const size_t need = 2375424ull + (size_t)N_EDGES * NOUT * 2;

    hipMemsetAsync(stats, 0, 16384, stream);
    convW<<<NOUT, 256, 0, stream>>>(W, wt);

    if (ws_size >= need) {
        hipMemsetAsync(counts, 0, N_NODES * sizeof(int), stream);
        hist_dst<<<(N_EDGES + 255) / 256, 256, 0, stream>>>(dstp, counts);
        scan_nodes<<<1, 1024, 0, stream>>>(counts, offs, cursor);
        build_perm<<<(N_EDGES + 255) / 256, 256, 0, stream>>>(dstp, cursor, perm);

        edge_gemm<0><<<N_EDGES / 64, 256, 0, stream>>>(h, e, srcp, dstp, wt,
                stats, nullptr, nullptr, nullptr, zbuf);
        bn_finalize<<<1, 256, 0, stream>>>(stats, gamma, beta, scaleC, shiftC);
        node_gather<<<N_NODES / 4, 256, 0, stream>>>(zbuf, perm, offs, counts,
                scaleC, shiftC, h, out);
    } else {
        hipMemsetAsync(out, 0, (size_t)N_NODES * HIDDEN * sizeof(float), stream);
        edge_gemm<1><<<N_EDGES / 64, 256, 0, stream>>>(h, e, srcp, dstp, wt,
                stats, nullptr, nullptr, nullptr, nullptr);
        bn_finalize<<<1, 256, 0, stream>>>(stats, gamma, beta, scaleC, shiftC);
        edge_gemm<2><<<N_EDGES / 64, 256, 0, stream>>>(h, e, srcp, dstp, wt,
                stats, scaleC, shiftC, out, nullptr);
        node_finalize<<<N_NODES * HIDDEN / (4 * 256), 256, 0, stream>>>(h, out);
    }
}